// Round 2
// baseline (18.730 us; speedup 1.0000x reference)
//
#include <hip/hip_runtime.h>
#include <hip/hip_bf16.h>
#include <math.h>

#define T_STEPS 1024
#define BATCH_N 256
#define HID 8
#define TOT1 (T_STEPS * BATCH_N * HID)   // 2,097,152 floats
// out_size = TOT1 + 2*BATCH_N*HID = 2,101,248 = 1026 rows of 2048

// One fused kernel. Every 256-thread block:
//   phase 1 (sim): wave w (of 4) simulates the 8-qubit 2-layer circuit for
//     param set w. State = 256 real amplitudes, 4/lane: flat i = (r<<6)|lane,
//     qubit q <-> flat bit (7-q). Layer-1 Ry on |0..0> is a product state
//     (computed analytically, no shuffles); CNOT ladders + layer-2 Ry use
//     __shfl_xor / register permutes. Wave-synchronous, no barriers.
//   phase 2 (write): block b writes one 2048-elem row of the output with
//     block-uniform values from the closed-form recurrence
//     c_t = i*g*(1-f^(t+1))/(1-f),  a_t = o*tanh(c_t),
//     outs[t,b,h] = a_t*rowsum(Wp)[h] + bp[h];  row 1024 = hx, row 1025 = cx.
__global__ __launch_bounds__(256) void qlstm_fused(
    const float* __restrict__ pf, const float* __restrict__ pi_,
    const float* __restrict__ pu, const float* __restrict__ po,
    const float* __restrict__ Wp, const float* __restrict__ bp,
    float* __restrict__ out) {
  const int tid  = threadIdx.x;
  const int lane = tid & 63;
  const int w    = tid >> 6;
  const float* p = (w == 0) ? pf : (w == 1) ? pi_ : (w == 2) ? pu : po;

  __shared__ float ev[4];
  __shared__ float swr[HID], sbr[HID];
  if (tid < HID) {
    float s = 0.0f;
    #pragma unroll
    for (int q = 0; q < 8; ++q) s += Wp[tid * 8 + q];
    swr[tid] = s;
    sbr[tid] = bp[tid];
  }

  // sin/cos of all 16 half-angles (wave-uniform values)
  float sn[16], cs[16];
  #pragma unroll
  for (int k = 0; k < 16; ++k) {
    const float th = 0.5f * p[k];
    sn[k] = sinf(th);
    cs[k] = cosf(th);
  }

  // Layer-1 Ry applied to |0..0> analytically: amp(i) = prod_b F_b where
  // F_b = bit_b(i) ? sn[7-b] : cs[7-b]  (qubit index = 7 - flat bit).
  float lp = 1.0f;
  #pragma unroll
  for (int b = 0; b < 6; ++b) lp *= ((lane >> b) & 1) ? sn[7 - b] : cs[7 - b];
  float amp[4];
  #pragma unroll
  for (int r = 0; r < 4; ++r)
    amp[r] = lp * ((r & 1) ? sn[1] : cs[1]) * ((r & 2) ? sn[0] : cs[0]);

  #pragma unroll
  for (int pass = 0; pass < 2; ++pass) {
    if (pass == 1) {
      // Layer-2 Ry gates
      #pragma unroll
      for (int q = 0; q < 8; ++q) {
        const int b = 7 - q;
        const float co = cs[8 + q], si = sn[8 + q];
        if (b == 7) {            // register bit 1: pairs (0,2),(1,3)
          float n0 = co * amp[0] - si * amp[2];
          float n2 = si * amp[0] + co * amp[2];
          float n1 = co * amp[1] - si * amp[3];
          float n3 = si * amp[1] + co * amp[3];
          amp[0] = n0; amp[1] = n1; amp[2] = n2; amp[3] = n3;
        } else if (b == 6) {     // register bit 0: pairs (0,1),(2,3)
          float n0 = co * amp[0] - si * amp[1];
          float n1 = si * amp[0] + co * amp[1];
          float n2 = co * amp[2] - si * amp[3];
          float n3 = si * amp[2] + co * amp[3];
          amp[0] = n0; amp[1] = n1; amp[2] = n2; amp[3] = n3;
        } else {                 // lane bit b: shuffle partner
          const int m = 1 << b;
          const bool hi = (lane & m) != 0;
          #pragma unroll
          for (int r = 0; r < 4; ++r) {
            float part = __shfl_xor(amp[r], m, 64);
            amp[r] = hi ? (si * part + co * amp[r])
                        : (co * amp[r] - si * part);
          }
        }
      }
    }
    // CNOT ladder (0,1),(1,2),...,(6,7),(7,0):
    // new[i] = (i has ctrl bit) ? old[i ^ tgt_bit] : old[i]
    #pragma unroll
    for (int q = 0; q < 8; ++q) {
      const int ctrl = q, tgt = (q + 1) & 7;
      const int cb = 7 - ctrl, tb = 7 - tgt;
      if (tb >= 6) {             // target in register bits
        const int rt = 1 << (tb - 6);
        float na[4];
        #pragma unroll
        for (int r = 0; r < 4; ++r) {
          const bool cond = (cb >= 6) ? (((r >> (cb - 6)) & 1) != 0)
                                      : (((lane >> cb) & 1) != 0);
          na[r] = cond ? amp[r ^ rt] : amp[r];
        }
        #pragma unroll
        for (int r = 0; r < 4; ++r) amp[r] = na[r];
      } else {                   // target in lane bits
        const int m = 1 << tb;
        #pragma unroll
        for (int r = 0; r < 4; ++r) {
          float part = __shfl_xor(amp[r], m, 64);
          const bool cond = (cb >= 6) ? (((r >> (cb - 6)) & 1) != 0)
                                      : (((lane >> cb) & 1) != 0);
          amp[r] = cond ? part : amp[r];
        }
      }
    }
  }

  // <Z> on qubit 7 (= flat bit 0 = lane bit 0)
  float v = amp[0] * amp[0] + amp[1] * amp[1] +
            amp[2] * amp[2] + amp[3] * amp[3];
  v = (lane & 1) ? -v : v;
  #pragma unroll
  for (int off = 1; off < 64; off <<= 1) v += __shfl_xor(v, off, 64);
  if (lane == 0) ev[w] = v;
  __syncthreads();

  // Gate scalars (block-uniform). f = sigmoid in (0.269,0.731): 1-f safe,
  // f^1024 underflows cleanly inside expf.
  const float f   = 1.0f / (1.0f + expf(-ev[0]));
  const float ii  = 1.0f / (1.0f + expf(-ev[1]));
  const float g   = tanhf(ev[2]);
  const float o   = 1.0f / (1.0f + expf(-ev[3]));
  const float inv = ii * g / (1.0f - f);
  const float lf  = logf(f);

  const int blk = blockIdx.x;      // 0..1023 outs rows, 1024 hx, 1025 cx
  float vals[8];
  if (blk <= T_STEPS) {
    const int t = (blk < T_STEPS) ? blk : (T_STEPS - 1);   // hx row = a_{T-1}
    const float c  = inv * (1.0f - expf((float)(t + 1) * lf));
    const float at = o * tanhf(c);
    #pragma unroll
    for (int h = 0; h < HID; ++h) vals[h] = fmaf(at, swr[h], sbr[h]);
  } else {
    const float cT = inv * (1.0f - expf((float)T_STEPS * lf));
    #pragma unroll
    for (int h = 0; h < HID; ++h) vals[h] = cT;
  }

  float* dst = out + (size_t)blk * 2048 + tid * 8;
  *reinterpret_cast<float4*>(dst)     = make_float4(vals[0], vals[1], vals[2], vals[3]);
  *reinterpret_cast<float4*>(dst + 4) = make_float4(vals[4], vals[5], vals[6], vals[7]);
}

extern "C" void kernel_launch(void* const* d_in, const int* in_sizes, int n_in,
                              void* d_out, int out_size, void* d_ws, size_t ws_size,
                              hipStream_t stream) {
  // setup_inputs order:
  // 0 inputs, 1 Wf, 2 bf, 3 Wi, 4 bi, 5 Wu, 6 bu, 7 Wo, 8 bo,
  // 9 pf, 10 pi, 11 pu, 12 po, 13 Wp, 14 bp
  const float* pf  = (const float*)d_in[9];
  const float* pi_ = (const float*)d_in[10];
  const float* pu  = (const float*)d_in[11];
  const float* po  = (const float*)d_in[12];
  const float* Wp  = (const float*)d_in[13];
  const float* bp  = (const float*)d_in[14];
  float* out = (float*)d_out;

  const int blocks = out_size / 2048;           // 1026
  qlstm_fused<<<blocks, 256, 0, stream>>>(pf, pi_, pu, po, Wp, bp, out);
}

// Round 3
// 13.378 us; speedup vs baseline: 1.4000x; 1.4000x over previous
//
#include <hip/hip_runtime.h>
#include <hip/hip_bf16.h>
#include <math.h>

#define T_STEPS 1024
#define BATCH_N 256
#define HID 8
#define N_ROWS 1026   // 1024 outs rows + hx + cx; each row = 2048 floats
#define GRID_B 512

// Fused kernel, 512 blocks x 256 threads.
//
// Phase 1 (sim): wave w (of 4) computes <Z_q7> for param set w of the
// 8-qubit, 2-layer Ry+CNOT-ladder circuit. 256 real amplitudes, 4/lane:
// slot x = (r<<6)|lane, qubit q <-> flat bit (7-q).
//
// CNOT ladders are GF(2)-linear basis permutations Λ and are FOLDED OUT:
//  - layer-1 Ry on |0..0> is a product state, kept in slot coords
//    (ladder 1 becomes the coordinate map w = Λ(x); data never moves);
//  - layer-2 Ry on bit b pairs slot x with x ^ Λ^{-1}(1<<b), role bit
//    = bit_b(Λ(x));
//  - ladder 2 + measurement fold to sign(x) = parity(Λ(x)).
// Λ = suffix-parity map: S = x^(x>>1); S^=S>>2; S^=S>>4;
//     Λ(x) = (S & 0x7F) | ((bit7(x) ^ (S&1)) << 7).
// Partner masks Λ^{-1}(1<<b) for b=7..0:
//     0xC0, 0x60, 0x30, 0x18, 0x0C, 0x06, 0x03, 0xC1.
//
// Phase 2 (write): closed-form recurrence (block-uniform):
//   c_t = i*g*(1-f^(t+1))/(1-f),  a_t = o*tanh(c_t)
//   outs[t,b,h] = a_t*rowsum(Wp)[h] + bp[h]; row 1024 = hx, row 1025 = cx.
// Grid-stride over 1026 rows; each thread stores 32 contiguous bytes.
__global__ __launch_bounds__(256) void qlstm_fused(
    const float* __restrict__ pf, const float* __restrict__ pi_,
    const float* __restrict__ pu, const float* __restrict__ po,
    const float* __restrict__ Wp, const float* __restrict__ bp,
    float* __restrict__ out) {
  const int tid  = threadIdx.x;
  const int lane = tid & 63;
  const int w    = tid >> 6;
  const float* p = (w == 0) ? pf : (w == 1) ? pi_ : (w == 2) ? pu : po;

  __shared__ float ev[4];
  __shared__ float swr[HID], sbr[HID];
  if (tid < HID) {
    float s = 0.0f;
    #pragma unroll
    for (int q = 0; q < 8; ++q) s += Wp[tid * 8 + q];
    swr[tid] = s;
    sbr[tid] = bp[tid];
  }

  // half-angle sin/cos (wave-uniform)
  float sn[16], cs[16];
  #pragma unroll
  for (int k = 0; k < 16; ++k) {
    const float th = 0.5f * p[k];
    sn[k] = sinf(th);
    cs[k] = cosf(th);
  }

  // Lx[r] = Λ(slot), msign[r] = measurement sign = (-1)^parity(Λ(slot))
  int   Lx[4];
  float msign[4];
  #pragma unroll
  for (int r = 0; r < 4; ++r) {
    const int x = (r << 6) | lane;
    int S = x ^ (x >> 1); S ^= S >> 2; S ^= S >> 4;          // suffix parities
    Lx[r] = (S & 0x7F) | ((((x >> 7) ^ S) & 1) << 7);
    msign[r] = (__popc(Lx[r]) & 1) ? -1.0f : 1.0f;
  }

  // Layer-1 Ry product state: amp(x) = prod_b (bit_b(x) ? sn[7-b] : cs[7-b])
  float lp = 1.0f;
  #pragma unroll
  for (int b = 0; b < 6; ++b) lp *= ((lane >> b) & 1) ? sn[7 - b] : cs[7 - b];
  float amp[4];
  #pragma unroll
  for (int r = 0; r < 4; ++r)
    amp[r] = lp * ((r & 1) ? sn[1] : cs[1]) * ((r & 2) ? sn[0] : cs[0]);

  // Layer-2 Ry gates in folded coordinates.
  // Gate q: angle idx 8+q, acts on bit b = 7-q of the ACTUAL index:
  //   partner slot = x ^ m'(b); role = bit_b(Lx); new = c*a ± s*partner.
  {
    float pv[4];
    // q=0: m'=0xC0 (pure register swap r^3), role bit7
    #pragma unroll
    for (int r = 0; r < 4; ++r) pv[r] = amp[r ^ 3];
    #pragma unroll
    for (int r = 0; r < 4; ++r)
      amp[r] = fmaf(cs[8], amp[r], (((Lx[r] >> 7) & 1) ? sn[8] : -sn[8]) * pv[r]);
    // q=1: m'=0x60 (r^1, lane^32), role bit6
    #pragma unroll
    for (int r = 0; r < 4; ++r) pv[r] = __shfl_xor(amp[r ^ 1], 32, 64);
    #pragma unroll
    for (int r = 0; r < 4; ++r)
      amp[r] = fmaf(cs[9], amp[r], (((Lx[r] >> 6) & 1) ? sn[9] : -sn[9]) * pv[r]);
    // q=2..6: pure lane masks 0x30,0x18,0x0C,0x06,0x03; role bits 5..1
    #pragma unroll
    for (int q = 2; q <= 6; ++q) {
      const int b = 7 - q;
      const int m = (3 << (b - 1)) & 63;   // 0x30,0x18,0x0C,0x06,0x03
      #pragma unroll
      for (int r = 0; r < 4; ++r) pv[r] = __shfl_xor(amp[r], m, 64);
      #pragma unroll
      for (int r = 0; r < 4; ++r)
        amp[r] = fmaf(cs[8 + q], amp[r],
                      (((Lx[r] >> b) & 1) ? sn[8 + q] : -sn[8 + q]) * pv[r]);
    }
    // q=7: m'=0xC1 (r^3, lane^1), role bit0
    #pragma unroll
    for (int r = 0; r < 4; ++r) pv[r] = __shfl_xor(amp[r ^ 3], 1, 64);
    #pragma unroll
    for (int r = 0; r < 4; ++r)
      amp[r] = fmaf(cs[15], amp[r], ((Lx[r] & 1) ? sn[15] : -sn[15]) * pv[r]);
  }

  // <Z_q7> = sum msign * amp^2, wave butterfly reduce
  float v = msign[0] * amp[0] * amp[0] + msign[1] * amp[1] * amp[1] +
            msign[2] * amp[2] * amp[2] + msign[3] * amp[3] * amp[3];
  #pragma unroll
  for (int off = 1; off < 64; off <<= 1) v += __shfl_xor(v, off, 64);
  if (lane == 0) ev[w] = v;
  __syncthreads();

  // Gate scalars (block-uniform). f = sigmoid in (0.269,0.731): 1-f safe;
  // f^1024 underflows cleanly inside expf.
  const float f   = 1.0f / (1.0f + expf(-ev[0]));
  const float ii  = 1.0f / (1.0f + expf(-ev[1]));
  const float g   = tanhf(ev[2]);
  const float o   = 1.0f / (1.0f + expf(-ev[3]));
  const float inv = ii * g / (1.0f - f);
  const float lf  = logf(f);

  for (int row = blockIdx.x; row < N_ROWS; row += GRID_B) {
    float vals[8];
    if (row <= T_STEPS) {
      const int t = (row < T_STEPS) ? row : (T_STEPS - 1);   // hx = a_{T-1} row
      const float c  = inv * (1.0f - expf((float)(t + 1) * lf));
      const float at = o * tanhf(c);
      #pragma unroll
      for (int h = 0; h < HID; ++h) vals[h] = fmaf(at, swr[h], sbr[h]);
    } else {
      const float cT = inv * (1.0f - expf((float)T_STEPS * lf));
      #pragma unroll
      for (int h = 0; h < HID; ++h) vals[h] = cT;
    }
    float* dst = out + (size_t)row * 2048 + tid * 8;
    *reinterpret_cast<float4*>(dst)     = make_float4(vals[0], vals[1], vals[2], vals[3]);
    *reinterpret_cast<float4*>(dst + 4) = make_float4(vals[4], vals[5], vals[6], vals[7]);
  }
}

extern "C" void kernel_launch(void* const* d_in, const int* in_sizes, int n_in,
                              void* d_out, int out_size, void* d_ws, size_t ws_size,
                              hipStream_t stream) {
  // setup_inputs order:
  // 0 inputs, 1 Wf, 2 bf, 3 Wi, 4 bi, 5 Wu, 6 bu, 7 Wo, 8 bo,
  // 9 pf, 10 pi, 11 pu, 12 po, 13 Wp, 14 bp
  const float* pf  = (const float*)d_in[9];
  const float* pi_ = (const float*)d_in[10];
  const float* pu  = (const float*)d_in[11];
  const float* po  = (const float*)d_in[12];
  const float* Wp  = (const float*)d_in[13];
  const float* bp  = (const float*)d_in[14];
  float* out = (float*)d_out;

  qlstm_fused<<<GRID_B, 256, 0, stream>>>(pf, pi_, pu, po, Wp, bp, out);
}

// Round 4
// 10.255 us; speedup vs baseline: 1.8264x; 1.3046x over previous
//
#include <hip/hip_runtime.h>
#include <hip/hip_bf16.h>
#include <math.h>

#define T_STEPS 1024
#define BATCH_N 256
#define HID 8
#define N_ROWS 1026   // 1024 outs rows + hx + cx; each row = 2048 floats
#define GRID_B 512

// Native single-instruction transcendentals (accuracy ~1e-6, threshold 7e-3).
// v_sin/v_cos take REVOLUTIONS; v_exp/v_log are exp2/log2.
__device__ __forceinline__ float fexp2(float x) { return __builtin_amdgcn_exp2f(x); }
__device__ __forceinline__ float flog2(float x) { return __builtin_amdgcn_logf(x); }
__device__ __forceinline__ float frcp (float x) { return __builtin_amdgcn_rcpf(x); }
#define RCP_2PI 0.15915494309189535f
#define LOG2E   1.4426950408889634f
__device__ __forceinline__ float fsin(float rad) { return __builtin_amdgcn_sinf(rad * RCP_2PI); }
__device__ __forceinline__ float fcos(float rad) { return __builtin_amdgcn_cosf(rad * RCP_2PI); }
__device__ __forceinline__ float fsigmoid(float x) { return frcp(1.0f + fexp2(-LOG2E * x)); }
__device__ __forceinline__ float ftanh(float x) {
  // tanh(x) = 1 - 2/(e^{2x}+1); e^{2x} = 2^{2*log2e*x}
  return 1.0f - 2.0f * frcp(fexp2(2.0f * LOG2E * x) + 1.0f);
}

// Fused kernel, 512 blocks x 256 threads.
//
// Phase 1 (sim): wave w (of 4) computes <Z_q7> for param set w of the
// 8-qubit, 2-layer Ry+CNOT-ladder circuit. 256 real amplitudes, 4/lane:
// slot x = (r<<6)|lane, qubit q <-> flat bit (7-q).
//
// CNOT ladders are GF(2)-linear basis permutations Λ, FOLDED OUT:
//  - layer-1 Ry on |0..0> is a product state, kept in slot coords;
//  - layer-2 Ry on bit b pairs slot x with x ^ Λ^{-1}(1<<b), role bit
//    = bit_b(Λ(x));
//  - ladder 2 + measurement fold to sign(x) = (-1)^parity(Λ(x)).
// Λ = suffix-parity map: S = x^(x>>1); S^=S>>2; S^=S>>4;
//     Λ(x) = (S & 0x7F) | ((bit7(x) ^ (S&1)) << 7).
// Partner masks Λ^{-1}(1<<b), b=7..0: 0xC0,0x60,0x30,0x18,0x0C,0x06,0x03,0xC1.
//
// Phase 2 (write): closed-form recurrence (block-uniform):
//   c_t = i*g*(1-f^(t+1))/(1-f),  a_t = o*tanh(c_t)
//   outs[t,b,h] = a_t*rowsum(Wp)[h] + bp[h]; row 1024 = hx, row 1025 = cx.
__global__ __launch_bounds__(256) void qlstm_fused(
    const float* __restrict__ pf, const float* __restrict__ pi_,
    const float* __restrict__ pu, const float* __restrict__ po,
    const float* __restrict__ Wp, const float* __restrict__ bp,
    float* __restrict__ out) {
  const int tid  = threadIdx.x;
  const int lane = tid & 63;
  const int w    = tid >> 6;
  const float* p = (w == 0) ? pf : (w == 1) ? pi_ : (w == 2) ? pu : po;

  __shared__ float ev[4];
  __shared__ float swr[HID], sbr[HID];
  if (tid < HID) {
    float s = 0.0f;
    #pragma unroll
    for (int q = 0; q < 8; ++q) s += Wp[tid * 8 + q];
    swr[tid] = s;
    sbr[tid] = bp[tid];
  }

  // half-angle sin/cos (wave-uniform values, native v_sin/v_cos)
  float sn[16], cs[16];
  #pragma unroll
  for (int k = 0; k < 16; ++k) {
    const float th = 0.5f * p[k];
    sn[k] = fsin(th);
    cs[k] = fcos(th);
  }

  // Lx[r] = Λ(slot), msign[r] = (-1)^parity(Λ(slot))
  int   Lx[4];
  float msign[4];
  #pragma unroll
  for (int r = 0; r < 4; ++r) {
    const int x = (r << 6) | lane;
    int S = x ^ (x >> 1); S ^= S >> 2; S ^= S >> 4;          // suffix parities
    Lx[r] = (S & 0x7F) | ((((x >> 7) ^ S) & 1) << 7);
    msign[r] = (__popc(Lx[r]) & 1) ? -1.0f : 1.0f;
  }

  // Layer-1 Ry product state: amp(x) = prod_b (bit_b(x) ? sn[7-b] : cs[7-b])
  float lp = 1.0f;
  #pragma unroll
  for (int b = 0; b < 6; ++b) lp *= ((lane >> b) & 1) ? sn[7 - b] : cs[7 - b];
  float amp[4];
  #pragma unroll
  for (int r = 0; r < 4; ++r)
    amp[r] = lp * ((r & 1) ? sn[1] : cs[1]) * ((r & 2) ? sn[0] : cs[0]);

  // Layer-2 Ry gates in folded coordinates.
  {
    float pv[4];
    // q=0: m'=0xC0 (register swap r^3), role bit7
    #pragma unroll
    for (int r = 0; r < 4; ++r) pv[r] = amp[r ^ 3];
    #pragma unroll
    for (int r = 0; r < 4; ++r)
      amp[r] = fmaf(cs[8], amp[r], (((Lx[r] >> 7) & 1) ? sn[8] : -sn[8]) * pv[r]);
    // q=1: m'=0x60 (r^1, lane^32), role bit6
    #pragma unroll
    for (int r = 0; r < 4; ++r) pv[r] = __shfl_xor(amp[r ^ 1], 32, 64);
    #pragma unroll
    for (int r = 0; r < 4; ++r)
      amp[r] = fmaf(cs[9], amp[r], (((Lx[r] >> 6) & 1) ? sn[9] : -sn[9]) * pv[r]);
    // q=2..6: lane masks 0x30,0x18,0x0C,0x06,0x03; role bits 5..1
    #pragma unroll
    for (int q = 2; q <= 6; ++q) {
      const int b = 7 - q;
      const int m = (3 << (b - 1)) & 63;
      #pragma unroll
      for (int r = 0; r < 4; ++r) pv[r] = __shfl_xor(amp[r], m, 64);
      #pragma unroll
      for (int r = 0; r < 4; ++r)
        amp[r] = fmaf(cs[8 + q], amp[r],
                      (((Lx[r] >> b) & 1) ? sn[8 + q] : -sn[8 + q]) * pv[r]);
    }
    // q=7: m'=0xC1 (r^3, lane^1), role bit0
    #pragma unroll
    for (int r = 0; r < 4; ++r) pv[r] = __shfl_xor(amp[r ^ 3], 1, 64);
    #pragma unroll
    for (int r = 0; r < 4; ++r)
      amp[r] = fmaf(cs[15], amp[r], ((Lx[r] & 1) ? sn[15] : -sn[15]) * pv[r]);
  }

  // <Z_q7> = sum msign * amp^2, wave butterfly reduce
  float v = msign[0] * amp[0] * amp[0] + msign[1] * amp[1] * amp[1] +
            msign[2] * amp[2] * amp[2] + msign[3] * amp[3] * amp[3];
  #pragma unroll
  for (int off = 1; off < 64; off <<= 1) v += __shfl_xor(v, off, 64);
  if (lane == 0) ev[w] = v;
  __syncthreads();

  // Gate scalars (block-uniform). f = sigmoid in (0.269,0.731).
  const float f   = fsigmoid(ev[0]);
  const float ii  = fsigmoid(ev[1]);
  const float g   = ftanh(ev[2]);
  const float o   = fsigmoid(ev[3]);
  const float inv = ii * g * frcp(1.0f - f);
  const float lf2 = flog2(f);                 // f^n = exp2(n*log2(f))

  for (int row = blockIdx.x; row < N_ROWS; row += GRID_B) {
    float vals[8];
    if (row <= T_STEPS) {
      const int t = (row < T_STEPS) ? row : (T_STEPS - 1);   // hx = a_{T-1} row
      const float c  = inv * (1.0f - fexp2((float)(t + 1) * lf2));
      const float at = o * ftanh(c);
      #pragma unroll
      for (int h = 0; h < HID; ++h) vals[h] = fmaf(at, swr[h], sbr[h]);
    } else {
      const float cT = inv * (1.0f - fexp2((float)T_STEPS * lf2));
      #pragma unroll
      for (int h = 0; h < HID; ++h) vals[h] = cT;
    }
    float* dst = out + (size_t)row * 2048 + tid * 8;
    *reinterpret_cast<float4*>(dst)     = make_float4(vals[0], vals[1], vals[2], vals[3]);
    *reinterpret_cast<float4*>(dst + 4) = make_float4(vals[4], vals[5], vals[6], vals[7]);
  }
}

extern "C" void kernel_launch(void* const* d_in, const int* in_sizes, int n_in,
                              void* d_out, int out_size, void* d_ws, size_t ws_size,
                              hipStream_t stream) {
  // setup_inputs order:
  // 0 inputs, 1 Wf, 2 bf, 3 Wi, 4 bi, 5 Wu, 6 bu, 7 Wo, 8 bo,
  // 9 pf, 10 pi, 11 pu, 12 po, 13 Wp, 14 bp
  const float* pf  = (const float*)d_in[9];
  const float* pi_ = (const float*)d_in[10];
  const float* pu  = (const float*)d_in[11];
  const float* po  = (const float*)d_in[12];
  const float* Wp  = (const float*)d_in[13];
  const float* bp  = (const float*)d_in[14];
  float* out = (float*)d_out;

  qlstm_fused<<<GRID_B, 256, 0, stream>>>(pf, pi_, pu, po, Wp, bp, out);
}